// Round 12
// baseline (326.068 us; speedup 1.0000x reference)
//
#include <hip/hip_runtime.h>
#include <hip/hip_bf16.h>

#define B_N 64
#define S_N 2048
#define E_N 512
#define A_N 512
#define SPN (B_N * S_N)   // 131072 rows

typedef __bf16 bf16x8 __attribute__((ext_vector_type(8)));
typedef float  f32x4  __attribute__((ext_vector_type(4)));

__device__ __forceinline__ unsigned int f2bfu(float f) {
  return (unsigned int)__builtin_bit_cast(unsigned short, (__bf16)f);
}

__device__ __forceinline__ float tanh_term(float x) {
  x = fminf(9.f, fmaxf(-9.f, x));
  const float ex = __expf(2.f * x);
  return __fdividef(ex - 1.f, ex + 1.f);
}

// ------- K0a: pack W_enc fp32 [A][E] -> bf16, fragment-ordered for k_scores -
// chunk u = ((cb*8 + ks)*16 + c)*64 + l   (16 B each)
// holds W[a = cb*128 + (c&7)*16 + (l&15)][k = ks*64 + (c>>3)*32 + (l>>4)*8 + j]
__global__ __launch_bounds__(256) void k_pack(const float* __restrict__ W,
                                              unsigned short* __restrict__ Wp) {
  const int pk = blockIdx.x * 256 + threadIdx.x;      // [0, 32768)
  const int l = pk & 63, c = (pk >> 6) & 15, ks = (pk >> 10) & 7, cb = pk >> 13;
  const int a = cb * 128 + (c & 7) * 16 + (l & 15);
  const int k = ks * 64 + (c >> 3) * 32 + (l >> 4) * 8;
  const float* src = W + (size_t)a * E_N + k;
  const f32x4 u = *(const f32x4*)src;
  const f32x4 w = *(const f32x4*)(src + 4);
  uint4 o;
  o.x = f2bfu(u.x) | (f2bfu(u.y) << 16);
  o.y = f2bfu(u.z) | (f2bfu(u.w) << 16);
  o.z = f2bfu(w.x) | (f2bfu(w.y) << 16);
  o.w = f2bfu(w.z) | (f2bfu(w.w) << 16);
  *(uint4*)(Wp + (size_t)pk * 8) = o;
}

// ------- K0b: dec_proj[b][a] = dot(dec_hidden[b], W_dec[a]) ----------------
__global__ __launch_bounds__(256) void k_decproj(const float* __restrict__ dh,
                                                 const float* __restrict__ Wd,
                                                 float* __restrict__ decp) {
  const int b = blockIdx.x, tid = threadIdx.x;
  __shared__ float h[E_N];
  h[tid] = dh[b * E_N + tid];
  h[tid + 256] = dh[b * E_N + 256 + tid];
  __syncthreads();
  for (int a = tid; a < A_N; a += 256) {
    const float* wr = Wd + (size_t)a * E_N;
    float s = 0.f;
    #pragma unroll 8
    for (int e = 0; e < E_N; e += 4) {
      const float4 w4 = *(const float4*)(wr + e);
      s += w4.x * h[e] + w4.y * h[e + 1] + w4.z * h[e + 2] + w4.w * h[e + 3];
    }
    decp[b * A_N + a] = s;
  }
}

// ------- K1: pipelined 128x128x(K=512) GEMM + fused tanh epilogue -----------
// 256 thr = 4 waves (2 row x 2 col of 64x64). BK=64, A+B double-buffered in
// fragment-ordered LDS, ONE barrier per K-step, issue-early/write-late staging.
// Partial scores per 128-col block -> sp[cb], summed in k_softmax.
#define ABUF 16384

__global__ __launch_bounds__(256) void k_scores(
    const float* __restrict__ enc, const unsigned short* __restrict__ Wp,
    const float* __restrict__ decp, const float* __restrict__ vvec,
    float* __restrict__ sp) {
  __shared__ __align__(16) unsigned char lA[2 * ABUF];
  __shared__ __align__(16) unsigned char lB[2 * ABUF];
  __shared__ float red[4][64];
  const int tid = threadIdx.x;
  const int lane = tid & 63, wv = tid >> 6, q = lane >> 4, ln = lane & 15;
  const int wr = wv & 1, wc = wv >> 1;
  // XCD-chunked bijective swizzle: blocks on one XCD get consecutive o
  const int o = (blockIdx.x & 7) * 512 + (blockIdx.x >> 3);
  const int rg = o >> 2, cb = o & 3;
  const int row0 = rg * 128, b = rg >> 4;

  // epilogue constants
  float vv[4], dp[4];
  #pragma unroll
  for (int nt = 0; nt < 4; ++nt) {
    const int col = cb * 128 + wc * 64 + nt * 16 + ln;
    vv[nt] = vvec[col];
    dp[nt] = decp[b * A_N + col];
  }

  // staging geometry: thread handles 4 fragment-chunks (same (c,l) for A & B)
  const float* pA[4];
  const unsigned short* pB[4];
  int w16[4];
  #pragma unroll
  for (int i = 0; i < 4; ++i) {
    const int g = i * 256 + tid, c = g >> 6, l = g & 63;
    const int row = (c & 7) * 16 + (l & 15), kof = (c >> 3) * 32 + (l >> 4) * 8;
    pA[i] = enc + (size_t)(row0 + row) * E_N + kof;
    pB[i] = Wp + ((size_t)(cb * 128 + c) * 64 + l) * 8;
    w16[i] = c * 1024 + l * 16;
  }

  f32x4 La[8];
  uint4 Lb[4];

#define ISSUE(KS)                                             \
  {                                                           \
    _Pragma("unroll")                                         \
    for (int i = 0; i < 4; ++i) {                             \
      La[2 * i]     = *(const f32x4*)(pA[i] + (KS) * 64);     \
      La[2 * i + 1] = *(const f32x4*)(pA[i] + (KS) * 64 + 4); \
      Lb[i]         = *(const uint4*)(pB[i] + (KS) * 8192);   \
    }                                                         \
  }

#define WRITE(DB)                                                     \
  {                                                                   \
    _Pragma("unroll")                                                 \
    for (int i = 0; i < 4; ++i) {                                     \
      uint4 oo;                                                       \
      oo.x = f2bfu(La[2 * i].x) | (f2bfu(La[2 * i].y) << 16);         \
      oo.y = f2bfu(La[2 * i].z) | (f2bfu(La[2 * i].w) << 16);         \
      oo.z = f2bfu(La[2 * i + 1].x) | (f2bfu(La[2 * i + 1].y) << 16); \
      oo.w = f2bfu(La[2 * i + 1].z) | (f2bfu(La[2 * i + 1].w) << 16); \
      *(uint4*)(lA + (DB) * ABUF + w16[i]) = oo;                      \
      *(uint4*)(lB + (DB) * ABUF + w16[i]) = Lb[i];                   \
    }                                                                 \
  }

  // prologue: stage ks=0 into buf 0
  ISSUE(0);
  WRITE(0);
  __syncthreads();

  f32x4 acc[4][4] = {};
  #pragma unroll 2
  for (int ks = 0; ks < 8; ++ks) {
    const int buf = ks & 1;
    if (ks < 7) ISSUE(ks + 1);          // issue-early (hides under MFMAs)
    #pragma unroll
    for (int kt = 0; kt < 2; ++kt) {
      bf16x8 afr[4], bfr[4];
      #pragma unroll
      for (int mt = 0; mt < 4; ++mt)
        afr[mt] = *(const bf16x8*)(
            lA + buf * ABUF + (kt * 8 + wr * 4 + mt) * 1024 + lane * 16);
      #pragma unroll
      for (int nt = 0; nt < 4; ++nt)
        bfr[nt] = *(const bf16x8*)(
            lB + buf * ABUF + (kt * 8 + wc * 4 + nt) * 1024 + lane * 16);
      #pragma unroll
      for (int mt = 0; mt < 4; ++mt)
        #pragma unroll
        for (int nt = 0; nt < 4; ++nt)
          acc[mt][nt] = __builtin_amdgcn_mfma_f32_16x16x32_bf16(
              afr[mt], bfr[nt], acc[mt][nt], 0, 0, 0);
    }
    if (ks < 7) WRITE(buf ^ 1);         // write-late into alternate buffer
    __syncthreads();                     // one barrier per K-step
  }

  // ---- fused epilogue: tanh(x + decp) * v; partial over this block's cols --
  #pragma unroll
  for (int mt = 0; mt < 4; ++mt) {
    #pragma unroll
    for (int r = 0; r < 4; ++r) {
      float s = 0.f;
      #pragma unroll
      for (int nt = 0; nt < 4; ++nt)
        s = fmaf(tanh_term(acc[mt][nt][r] + dp[nt]), vv[nt], s);
      s += __shfl_xor(s, 1);
      s += __shfl_xor(s, 2);
      s += __shfl_xor(s, 4);
      s += __shfl_xor(s, 8);
      if (ln == 0) red[wv][mt * 16 + q * 4 + r] = s;
    }
  }
  __syncthreads();
  if (tid < 128) {
    const int hw = tid >> 6, rl = tid & 63;
    sp[(size_t)cb * SPN + row0 + tid] = red[hw][rl] + red[2 + hw][rl];
  }
#undef ISSUE
#undef WRITE
}

// ------- K2: softmax over S per b (sums the 4 col-block partials) -----------
__global__ __launch_bounds__(256) void k_softmax(const float* __restrict__ sp,
                                                 float* __restrict__ attn) {
  const int b = blockIdx.x, tid = threadIdx.x;
  float l[8];
  float mx = -3.4e38f;
  #pragma unroll
  for (int i = 0; i < 8; ++i) {
    const size_t idx = (size_t)b * S_N + i * 256 + tid;
    l[i] = (sp[idx] + sp[SPN + idx]) + (sp[2 * (size_t)SPN + idx] + sp[3 * (size_t)SPN + idx]);
    mx = fmaxf(mx, l[i]);
  }
  #pragma unroll
  for (int m = 1; m < 64; m <<= 1) mx = fmaxf(mx, __shfl_xor(mx, m));
  __shared__ float sred[8];
  if ((tid & 63) == 0) sred[tid >> 6] = mx;
  __syncthreads();
  mx = fmaxf(fmaxf(sred[0], sred[1]), fmaxf(sred[2], sred[3]));
  float se = 0.f;
  #pragma unroll
  for (int i = 0; i < 8; ++i) { l[i] = __expf(l[i] - mx); se += l[i]; }
  #pragma unroll
  for (int m = 1; m < 64; m <<= 1) se += __shfl_xor(se, m);
  if ((tid & 63) == 0) sred[4 + (tid >> 6)] = se;
  __syncthreads();
  se = sred[4] + sred[5] + sred[6] + sred[7];
  const float inv = 1.f / se;
  #pragma unroll
  for (int i = 0; i < 8; ++i) attn[b * S_N + i * 256 + tid] = l[i] * inv;
}

// ------- K3: context[b][e] = sum_s w[b][s] * enc[b][s][e] -------------------
__global__ __launch_bounds__(512) void k_context(const float* __restrict__ enc,
                                                 const float* __restrict__ attn,
                                                 float* __restrict__ ctx) {
  const int blk = blockIdx.x;
  const int b = blk >> 2, eq = blk & 3;
  const int tid = threadIdx.x;
  const int te = tid & 31, sg = tid >> 5;   // 16 s-groups of 128 rows
  const int e0 = eq * 128 + te * 4;
  const float* ep = enc + (size_t)b * S_N * E_N + e0;
  const float* wp = attn + b * S_N;
  f32x4 acc = {0.f, 0.f, 0.f, 0.f};
  const int s0 = sg * 128;
  #pragma unroll 4
  for (int s = s0; s < s0 + 128; ++s) {
    const float w = wp[s];
    const f32x4 ev = *(const f32x4*)(ep + (size_t)s * E_N);
    acc += w * ev;
  }
  __shared__ f32x4 red[16][32];
  red[sg][te] = acc;
  __syncthreads();
  if (sg == 0) {
    f32x4 t = red[0][te];
    #pragma unroll
    for (int g = 1; g < 16; ++g) t += red[g][te];
    *(f32x4*)(ctx + (size_t)b * E_N + e0) = t;
  }
}

// ------- launch -------------------------------------------------------------
extern "C" void kernel_launch(void* const* d_in, const int* in_sizes, int n_in,
                              void* d_out, int out_size, void* d_ws, size_t ws_size,
                              hipStream_t stream) {
  const float* enc = (const float*)d_in[0];
  const float* dh  = (const float*)d_in[1];
  const float* We  = (const float*)d_in[2];
  const float* Wd  = (const float*)d_in[3];
  const float* v   = (const float*)d_in[4];

  float* out_ctx  = (float*)d_out;
  float* out_attn = out_ctx + B_N * E_N;

  float* sp   = (float*)d_ws;                         // 4 x 131072 f32 partials
  float* decp = sp + 4 * (size_t)SPN;                 // 32768 f32
  unsigned short* Wp = (unsigned short*)(decp + B_N * A_N);  // 262144 bf16 packed

  k_pack   <<<128, 256, 0, stream>>>(We, Wp);
  k_decproj<<<B_N, 256, 0, stream>>>(dh, Wd, decp);
  k_scores <<<4096, 256, 0, stream>>>(enc, Wp, decp, v, sp);
  k_softmax<<<B_N, 256, 0, stream>>>(sp, out_attn);
  k_context<<<B_N * 4, 512, 0, stream>>>(enc, out_attn, out_ctx);
}

// Round 13
// 256.795 us; speedup vs baseline: 1.2698x; 1.2698x over previous
//
#include <hip/hip_runtime.h>
#include <hip/hip_bf16.h>

#define B_N 64
#define S_N 2048
#define E_N 512
#define A_N 512
#define SPN (B_N * S_N)   // 131072 rows

typedef __bf16 bf16x8 __attribute__((ext_vector_type(8)));
typedef float  f32x4  __attribute__((ext_vector_type(4)));

__device__ __forceinline__ unsigned int f2bfu(float f) {
  return (unsigned int)__builtin_bit_cast(unsigned short, (__bf16)f);
}

__device__ __forceinline__ float tanh_term(float x) {
  x = fminf(9.f, fmaxf(-9.f, x));
  const float ex = __expf(2.f * x);
  return __fdividef(ex - 1.f, ex + 1.f);
}

// async 16B/lane global->LDS copy (lds base must be wave-uniform)
__device__ __forceinline__ void gl16(const void* g, void* l) {
  __builtin_amdgcn_global_load_lds(
      (const __attribute__((address_space(1))) unsigned int*)g,
      (__attribute__((address_space(3))) unsigned int*)l, 16, 0, 0);
}

// ------- K0a: pack W_enc fp32 [A][E] -> bf16 fragment-chunk order -----------
// chunk id = ks*64 + cb, cb = c16*2 + kt; lane l (16B) holds
// W[a = c16*16 + (l&15)][k = ks*64 + kt*32 + (l>>4)*8 + j], j=0..7
__global__ __launch_bounds__(256) void k_pack(const float* __restrict__ W,
                                              unsigned short* __restrict__ Wp) {
  const int pk = blockIdx.x * 256 + threadIdx.x;      // [0, 32768)
  const int l = pk & 63, cb = (pk >> 6) & 63, ks = pk >> 12;
  const int c16 = cb >> 1, kt = cb & 1;
  const int a = c16 * 16 + (l & 15);
  const int k = ks * 64 + kt * 32 + (l >> 4) * 8;
  const float* src = W + (size_t)a * E_N + k;
  const f32x4 u = *(const f32x4*)src;
  const f32x4 w = *(const f32x4*)(src + 4);
  uint4 o;
  o.x = f2bfu(u.x) | (f2bfu(u.y) << 16);
  o.y = f2bfu(u.z) | (f2bfu(u.w) << 16);
  o.z = f2bfu(w.x) | (f2bfu(w.y) << 16);
  o.w = f2bfu(w.z) | (f2bfu(w.w) << 16);
  *(uint4*)(Wp + (size_t)pk * 8) = o;
}

// ------- K0b: dec_proj[b][a] = dot(dec_hidden[b], W_dec[a]) ----------------
__global__ __launch_bounds__(256) void k_decproj(const float* __restrict__ dh,
                                                 const float* __restrict__ Wd,
                                                 float* __restrict__ decp) {
  const int b = blockIdx.x, tid = threadIdx.x;
  __shared__ float h[E_N];
  h[tid] = dh[b * E_N + tid];
  h[tid + 256] = dh[b * E_N + 256 + tid];
  __syncthreads();
  for (int a = tid; a < A_N; a += 256) {
    const float* wr = Wd + (size_t)a * E_N;
    float s = 0.f;
    #pragma unroll 8
    for (int e = 0; e < E_N; e += 4) {
      const float4 w4 = *(const float4*)(wr + e);
      s += w4.x * h[e] + w4.y * h[e + 1] + w4.z * h[e + 2] + w4.w * h[e + 3];
    }
    decp[b * A_N + a] = s;
  }
}

// ------- K1: scores via BM=64 x BN=512 x BK=64 pipelined GEMM ---------------
// 512 thr = 8 waves; wave wv owns cols wv*64..+64 (acc[4][4]).
// B: global_load_lds from fragment-packed Wp, double-buffered (2x64KB).
// A: reg-staged fp32->bf16 (2 loads + cvt + 1 ds_write per wave), dbuf 2x8KB.
// One barrier per K-step; B prefetch lands during compute (m97 pattern).
__global__ __launch_bounds__(512) void k_scores(
    const float* __restrict__ enc, const unsigned short* __restrict__ Wp,
    const float* __restrict__ decp, const float* __restrict__ vvec,
    float* __restrict__ scores) {
  __shared__ __align__(16) unsigned char ldsA[2 * 8192];
  __shared__ __align__(16) unsigned char ldsB[2 * 65536];
  __shared__ float red[8][64];
  const int tid = threadIdx.x;
  const int lane = tid & 63, wv = tid >> 6, q = lane >> 4, ln = lane & 15;
  const int row0 = blockIdx.x * 64;
  const int b = row0 >> 11;
  const unsigned char* WpB = (const unsigned char*)Wp;

  // epilogue constants
  float vv[4], dp[4];
  #pragma unroll
  for (int nt = 0; nt < 4; ++nt) {
    const int col = wv * 64 + nt * 16 + ln;
    vv[nt] = vvec[col];
    dp[nt] = decp[b * A_N + col];
  }

  // A staging source: thread stages chunk c=wv: A[(wv>>1)*16+ln][(wv&1)*32+q*8..+8]
  const float* aSrc =
      enc + (size_t)(row0 + (wv >> 1) * 16 + ln) * E_N + (wv & 1) * 32 + q * 8;
  unsigned char* aDst = ldsA + wv * 1024 + lane * 16;   // + buf*8192

  // ---- prologue: stage ks=0 into buf 0 ----
  {
    const f32x4 a0 = *(const f32x4*)(aSrc);
    const f32x4 a1 = *(const f32x4*)(aSrc + 4);
    #pragma unroll
    for (int i = 0; i < 8; ++i)
      gl16(WpB + (size_t)(wv * 8 + i) * 1024 + lane * 16,
           ldsB + (wv * 8 + i) * 1024);
    uint4 o;
    o.x = f2bfu(a0.x) | (f2bfu(a0.y) << 16);
    o.y = f2bfu(a0.z) | (f2bfu(a0.w) << 16);
    o.z = f2bfu(a1.x) | (f2bfu(a1.y) << 16);
    o.w = f2bfu(a1.z) | (f2bfu(a1.w) << 16);
    *(uint4*)aDst = o;
  }
  __syncthreads();

  f32x4 acc[4][4] = {};
  #pragma unroll 1
  for (int ks = 0; ks < 8; ++ks) {
    const int buf = ks & 1;
    f32x4 a0, a1;
    if (ks < 7) {
      // issue-early: A regs + B async prefetch for ks+1 into alternate buffer
      a0 = *(const f32x4*)(aSrc + (ks + 1) * 64);
      a1 = *(const f32x4*)(aSrc + (ks + 1) * 64 + 4);
      #pragma unroll
      for (int i = 0; i < 8; ++i)
        gl16(WpB + (size_t)((ks + 1) * 64 + wv * 8 + i) * 1024 + lane * 16,
             ldsB + (buf ^ 1) * 65536 + (wv * 8 + i) * 1024);
    }
    // compute on buf
    #pragma unroll
    for (int kt = 0; kt < 2; ++kt) {
      bf16x8 afr[4], bfr[4];
      #pragma unroll
      for (int mt = 0; mt < 4; ++mt)
        afr[mt] = *(const bf16x8*)(
            ldsA + buf * 8192 + (mt * 2 + kt) * 1024 + lane * 16);
      #pragma unroll
      for (int nt = 0; nt < 4; ++nt)
        bfr[nt] = *(const bf16x8*)(
            ldsB + buf * 65536 + ((wv * 4 + nt) * 2 + kt) * 1024 + lane * 16);
      #pragma unroll
      for (int mt = 0; mt < 4; ++mt)
        #pragma unroll
        for (int nt = 0; nt < 4; ++nt)
          acc[mt][nt] = __builtin_amdgcn_mfma_f32_16x16x32_bf16(
              afr[mt], bfr[nt], acc[mt][nt], 0, 0, 0);
    }
    // write-late: A for ks+1 into alternate buffer
    if (ks < 7) {
      uint4 o;
      o.x = f2bfu(a0.x) | (f2bfu(a0.y) << 16);
      o.y = f2bfu(a0.z) | (f2bfu(a0.w) << 16);
      o.z = f2bfu(a1.x) | (f2bfu(a1.y) << 16);
      o.w = f2bfu(a1.z) | (f2bfu(a1.w) << 16);
      *(uint4*)(aDst + (buf ^ 1) * 8192) = o;
    }
    __syncthreads();
  }

  // ---- fused epilogue: tanh(x + decp) * v, cross-wave reduce over 512 cols -
  #pragma unroll
  for (int mt = 0; mt < 4; ++mt) {
    #pragma unroll
    for (int r = 0; r < 4; ++r) {
      float s = 0.f;
      #pragma unroll
      for (int nt = 0; nt < 4; ++nt)
        s = fmaf(tanh_term(acc[mt][nt][r] + dp[nt]), vv[nt], s);
      s += __shfl_xor(s, 1);
      s += __shfl_xor(s, 2);
      s += __shfl_xor(s, 4);
      s += __shfl_xor(s, 8);
      if (ln == 0) red[wv][mt * 16 + q * 4 + r] = s;
    }
  }
  __syncthreads();
  if (tid < 64) {
    float s = 0.f;
    #pragma unroll
    for (int w8 = 0; w8 < 8; ++w8) s += red[w8][tid];
    scores[row0 + tid] = s;
  }
}

// ------- K2: softmax over S per b -------------------------------------------
__global__ __launch_bounds__(256) void k_softmax(const float* __restrict__ scores,
                                                 float* __restrict__ attn) {
  const int b = blockIdx.x, tid = threadIdx.x;
  float l[8];
  float mx = -3.4e38f;
  #pragma unroll
  for (int i = 0; i < 8; ++i) {
    l[i] = scores[b * S_N + i * 256 + tid];
    mx = fmaxf(mx, l[i]);
  }
  #pragma unroll
  for (int m = 1; m < 64; m <<= 1) mx = fmaxf(mx, __shfl_xor(mx, m));
  __shared__ float sred[8];
  if ((tid & 63) == 0) sred[tid >> 6] = mx;
  __syncthreads();
  mx = fmaxf(fmaxf(sred[0], sred[1]), fmaxf(sred[2], sred[3]));
  float se = 0.f;
  #pragma unroll
  for (int i = 0; i < 8; ++i) { l[i] = __expf(l[i] - mx); se += l[i]; }
  #pragma unroll
  for (int m = 1; m < 64; m <<= 1) se += __shfl_xor(se, m);
  if ((tid & 63) == 0) sred[4 + (tid >> 6)] = se;
  __syncthreads();
  se = sred[4] + sred[5] + sred[6] + sred[7];
  const float inv = 1.f / se;
  #pragma unroll
  for (int i = 0; i < 8; ++i) attn[b * S_N + i * 256 + tid] = l[i] * inv;
}

// ------- K3: context[b][e] = sum_s w[b][s] * enc[b][s][e] -------------------
__global__ __launch_bounds__(512) void k_context(const float* __restrict__ enc,
                                                 const float* __restrict__ attn,
                                                 float* __restrict__ ctx) {
  const int blk = blockIdx.x;
  const int b = blk >> 2, eq = blk & 3;
  const int tid = threadIdx.x;
  const int te = tid & 31, sg = tid >> 5;   // 16 s-groups of 128 rows
  const int e0 = eq * 128 + te * 4;
  const float* ep = enc + (size_t)b * S_N * E_N + e0;
  const float* wp = attn + b * S_N;
  f32x4 acc = {0.f, 0.f, 0.f, 0.f};
  const int s0 = sg * 128;
  #pragma unroll 4
  for (int s = s0; s < s0 + 128; ++s) {
    const float w = wp[s];
    const f32x4 ev = *(const f32x4*)(ep + (size_t)s * E_N);
    acc += w * ev;
  }
  __shared__ f32x4 red[16][32];
  red[sg][te] = acc;
  __syncthreads();
  if (sg == 0) {
    f32x4 t = red[0][te];
    #pragma unroll
    for (int g = 1; g < 16; ++g) t += red[g][te];
    *(f32x4*)(ctx + (size_t)b * E_N + e0) = t;
  }
}

// ------- launch -------------------------------------------------------------
extern "C" void kernel_launch(void* const* d_in, const int* in_sizes, int n_in,
                              void* d_out, int out_size, void* d_ws, size_t ws_size,
                              hipStream_t stream) {
  const float* enc = (const float*)d_in[0];
  const float* dh  = (const float*)d_in[1];
  const float* We  = (const float*)d_in[2];
  const float* Wd  = (const float*)d_in[3];
  const float* v   = (const float*)d_in[4];

  float* out_ctx  = (float*)d_out;
  float* out_attn = out_ctx + B_N * E_N;

  float* scores = (float*)d_ws;                       // 131072 f32
  float* decp   = scores + SPN;                       // 32768 f32
  unsigned short* Wp = (unsigned short*)(decp + B_N * A_N);  // 262144 bf16 packed

  k_pack   <<<128, 256, 0, stream>>>(We, Wp);
  k_decproj<<<B_N, 256, 0, stream>>>(dh, Wd, decp);
  k_scores <<<SPN / 64, 512, 0, stream>>>(enc, Wp, decp, v, scores);
  k_softmax<<<B_N, 256, 0, stream>>>(scores, out_attn);
  k_context<<<B_N * 4, 512, 0, stream>>>(enc, out_attn, out_ctx);
}

// Round 14
// 234.277 us; speedup vs baseline: 1.3918x; 1.0961x over previous
//
#include <hip/hip_runtime.h>
#include <hip/hip_bf16.h>

#define B_N 64
#define S_N 2048
#define E_N 512
#define A_N 512
#define SPN (B_N * S_N)   // 131072 rows

typedef __bf16 bf16x8 __attribute__((ext_vector_type(8)));
typedef float  f32x4  __attribute__((ext_vector_type(4)));

__device__ __forceinline__ unsigned int f2bfu(float f) {
  return (unsigned int)__builtin_bit_cast(unsigned short, (__bf16)f);
}

__device__ __forceinline__ float tanh_term(float x) {
  x = fminf(9.f, fmaxf(-9.f, x));
  const float ex = __expf(2.f * x);
  return __fdividef(ex - 1.f, ex + 1.f);
}

// async 16B/lane global->LDS copy (lds base wave-uniform; global addr per-lane)
__device__ __forceinline__ void gl16(const void* g, void* l) {
  __builtin_amdgcn_global_load_lds(
      (const __attribute__((address_space(1))) unsigned int*)g,
      (__attribute__((address_space(3))) unsigned int*)l, 16, 0, 0);
}

// ------- K0a: pack W_enc fp32 [A][E] -> bf16, fragment-chunk order ----------
// chunk u = ((cb*8 + ks)*16 + c)*64 + l   (16 B each)
// holds W[a = cb*128 + (c&7)*16 + (l&15)][k = ks*64 + (c>>3)*32 + (l>>4)*8 + j]
__global__ __launch_bounds__(256) void k_pack(const float* __restrict__ W,
                                              unsigned short* __restrict__ Wp) {
  const int pk = blockIdx.x * 256 + threadIdx.x;      // [0, 32768)
  const int l = pk & 63, c = (pk >> 6) & 15, ks = (pk >> 10) & 7, cb = pk >> 13;
  const int a = cb * 128 + (c & 7) * 16 + (l & 15);
  const int k = ks * 64 + (c >> 3) * 32 + (l >> 4) * 8;
  const float* src = W + (size_t)a * E_N + k;
  const f32x4 u = *(const f32x4*)src;
  const f32x4 w = *(const f32x4*)(src + 4);
  uint4 o;
  o.x = f2bfu(u.x) | (f2bfu(u.y) << 16);
  o.y = f2bfu(u.z) | (f2bfu(u.w) << 16);
  o.z = f2bfu(w.x) | (f2bfu(w.y) << 16);
  o.w = f2bfu(w.z) | (f2bfu(w.w) << 16);
  *(uint4*)(Wp + (size_t)pk * 8) = o;
}

// ------- K0b: dec_proj[b][a] = dot(dec_hidden[b], W_dec[a]) ----------------
__global__ __launch_bounds__(256) void k_decproj(const float* __restrict__ dh,
                                                 const float* __restrict__ Wd,
                                                 float* __restrict__ decp) {
  const int b = blockIdx.x, tid = threadIdx.x;
  __shared__ float h[E_N];
  h[tid] = dh[b * E_N + tid];
  h[tid + 256] = dh[b * E_N + 256 + tid];
  __syncthreads();
  for (int a = tid; a < A_N; a += 256) {
    const float* wr = Wd + (size_t)a * E_N;
    float s = 0.f;
    #pragma unroll 8
    for (int e = 0; e < E_N; e += 4) {
      const float4 w4 = *(const float4*)(wr + e);
      s += w4.x * h[e] + w4.y * h[e + 1] + w4.z * h[e + 2] + w4.w * h[e + 3];
    }
    decp[b * A_N + a] = s;
  }
}

// ------- K1: m97-geometry GEMM + fused tanh: 128x128 tile, BK=64, 4 waves ---
// 256 thr = 4 waves (wr=wv&1 rows, wc=wv>>1 cols; 64x64 each). Single-buffered
// 16KB A + 16KB B in fragment order; 2 barriers/K-step; B via global_load_lds;
// A reg-staged fp32->bf16 (transient). ~3-4 blocks/CU hide the barrier drain.
__global__ __launch_bounds__(256, 3) void k_scores(
    const float* __restrict__ enc, const unsigned short* __restrict__ Wp,
    const float* __restrict__ decp, const float* __restrict__ vvec,
    float* __restrict__ sp) {
  __shared__ __align__(16) unsigned char lA[16384];
  __shared__ __align__(16) unsigned char lB[16384];
  __shared__ float red[4][64];
  const int tid = threadIdx.x;
  const int lane = tid & 63, wv = tid >> 6, q = lane >> 4, ln = lane & 15;
  const int wr = wv & 1, wc = wv >> 1;
  // XCD-chunked bijective swizzle (4096 = 8*512): same-XCD blocks consecutive
  const int o = (blockIdx.x & 7) * 512 + (blockIdx.x >> 3);
  const int rg = o >> 2, cb = o & 3;
  const int row0 = rg * 128, b = rg >> 4;
  const unsigned char* WpB = (const unsigned char*)Wp;

  // epilogue constants
  float vv[4], dp[4];
  #pragma unroll
  for (int nt = 0; nt < 4; ++nt) {
    const int col = cb * 128 + wc * 64 + nt * 16 + ln;
    vv[nt] = vvec[col];
    dp[nt] = decp[b * A_N + col];
  }

  // A staging geometry: 4 slots/thread; slot g=i*256+tid -> chunk c=g>>6,
  // lane-in-chunk l=g&63: row=(c&7)*16+(l&15), k-offset=(c>>3)*32+(l>>4)*8
  const float* aSrc[4];
  int aDst[4];
  #pragma unroll
  for (int i = 0; i < 4; ++i) {
    const int g = i * 256 + tid, c = g >> 6, l = g & 63;
    aSrc[i] = enc + (size_t)(row0 + (c & 7) * 16 + (l & 15)) * E_N +
              (c >> 3) * 32 + (l >> 4) * 8;
    aDst[i] = c * 1024 + l * 16;
  }

  f32x4 acc[4][4] = {};
  #pragma unroll 1
  for (int ks = 0; ks < 8; ++ks) {
    // ---- stage: B async (gl_lds), A through regs with fp32->bf16 ----
    #pragma unroll
    for (int i = 0; i < 4; ++i)
      gl16(WpB + (size_t)(((cb * 8 + ks) * 16 + wv * 4 + i) * 64) * 16 +
               lane * 16,
           lB + (wv * 4 + i) * 1024);
    #pragma unroll
    for (int i = 0; i < 4; ++i) {
      const f32x4 u = *(const f32x4*)(aSrc[i] + ks * 64);
      const f32x4 w = *(const f32x4*)(aSrc[i] + ks * 64 + 4);
      uint4 oo;
      oo.x = f2bfu(u.x) | (f2bfu(u.y) << 16);
      oo.y = f2bfu(u.z) | (f2bfu(u.w) << 16);
      oo.z = f2bfu(w.x) | (f2bfu(w.y) << 16);
      oo.w = f2bfu(w.z) | (f2bfu(w.w) << 16);
      *(uint4*)(lA + aDst[i]) = oo;
    }
    __syncthreads();
    // ---- compute: 32 MFMA over BK=64 ----
    #pragma unroll
    for (int kt = 0; kt < 2; ++kt) {
      bf16x8 afr[4], bfr[4];
      #pragma unroll
      for (int mt = 0; mt < 4; ++mt)
        afr[mt] = *(const bf16x8*)(
            lA + (kt * 8 + wr * 4 + mt) * 1024 + lane * 16);
      #pragma unroll
      for (int nt = 0; nt < 4; ++nt)
        bfr[nt] = *(const bf16x8*)(
            lB + (kt * 8 + wc * 4 + nt) * 1024 + lane * 16);
      #pragma unroll
      for (int mt = 0; mt < 4; ++mt)
        #pragma unroll
        for (int nt = 0; nt < 4; ++nt)
          acc[mt][nt] = __builtin_amdgcn_mfma_f32_16x16x32_bf16(
              afr[mt], bfr[nt], acc[mt][nt], 0, 0, 0);
    }
    __syncthreads();
  }

  // ---- fused epilogue: tanh(x + decp)*v, partial over this block's 128 cols
  #pragma unroll
  for (int mt = 0; mt < 4; ++mt) {
    #pragma unroll
    for (int r = 0; r < 4; ++r) {
      float s = 0.f;
      #pragma unroll
      for (int nt = 0; nt < 4; ++nt)
        s = fmaf(tanh_term(acc[mt][nt][r] + dp[nt]), vv[nt], s);
      s += __shfl_xor(s, 1);
      s += __shfl_xor(s, 2);
      s += __shfl_xor(s, 4);
      s += __shfl_xor(s, 8);
      if (ln == 0) red[wv][mt * 16 + q * 4 + r] = s;
    }
  }
  __syncthreads();
  if (tid < 128) {
    const int hr = tid >> 6, idx = tid & 63;   // hr = wr half
    sp[(size_t)cb * SPN + row0 + hr * 64 + idx] =
        red[hr][idx] + red[hr + 2][idx];
  }
}

// ------- K2: softmax over S per b (sums the 4 col-block partials) -----------
__global__ __launch_bounds__(256) void k_softmax(const float* __restrict__ sp,
                                                 float* __restrict__ attn) {
  const int b = blockIdx.x, tid = threadIdx.x;
  float l[8];
  float mx = -3.4e38f;
  #pragma unroll
  for (int i = 0; i < 8; ++i) {
    const size_t idx = (size_t)b * S_N + i * 256 + tid;
    l[i] = (sp[idx] + sp[SPN + idx]) +
           (sp[2 * (size_t)SPN + idx] + sp[3 * (size_t)SPN + idx]);
    mx = fmaxf(mx, l[i]);
  }
  #pragma unroll
  for (int m = 1; m < 64; m <<= 1) mx = fmaxf(mx, __shfl_xor(mx, m));
  __shared__ float sred[8];
  if ((tid & 63) == 0) sred[tid >> 6] = mx;
  __syncthreads();
  mx = fmaxf(fmaxf(sred[0], sred[1]), fmaxf(sred[2], sred[3]));
  float se = 0.f;
  #pragma unroll
  for (int i = 0; i < 8; ++i) { l[i] = __expf(l[i] - mx); se += l[i]; }
  #pragma unroll
  for (int m = 1; m < 64; m <<= 1) se += __shfl_xor(se, m);
  if ((tid & 63) == 0) sred[4 + (tid >> 6)] = se;
  __syncthreads();
  se = sred[4] + sred[5] + sred[6] + sred[7];
  const float inv = 1.f / se;
  #pragma unroll
  for (int i = 0; i < 8; ++i) attn[b * S_N + i * 256 + tid] = l[i] * inv;
}

// ------- K3: context[b][e] = sum_s w[b][s] * enc[b][s][e] -------------------
__global__ __launch_bounds__(512) void k_context(const float* __restrict__ enc,
                                                 const float* __restrict__ attn,
                                                 float* __restrict__ ctx) {
  const int blk = blockIdx.x;
  const int b = blk >> 2, eq = blk & 3;
  const int tid = threadIdx.x;
  const int te = tid & 31, sg = tid >> 5;   // 16 s-groups of 128 rows
  const int e0 = eq * 128 + te * 4;
  const float* ep = enc + (size_t)b * S_N * E_N + e0;
  const float* wp = attn + b * S_N;
  f32x4 acc = {0.f, 0.f, 0.f, 0.f};
  const int s0 = sg * 128;
  #pragma unroll 4
  for (int s = s0; s < s0 + 128; ++s) {
    const float w = wp[s];
    const f32x4 ev = *(const f32x4*)(ep + (size_t)s * E_N);
    acc += w * ev;
  }
  __shared__ f32x4 red[16][32];
  red[sg][te] = acc;
  __syncthreads();
  if (sg == 0) {
    f32x4 t = red[0][te];
    #pragma unroll
    for (int g = 1; g < 16; ++g) t += red[g][te];
    *(f32x4*)(ctx + (size_t)b * E_N + e0) = t;
  }
}

// ------- launch -------------------------------------------------------------
extern "C" void kernel_launch(void* const* d_in, const int* in_sizes, int n_in,
                              void* d_out, int out_size, void* d_ws, size_t ws_size,
                              hipStream_t stream) {
  const float* enc = (const float*)d_in[0];
  const float* dh  = (const float*)d_in[1];
  const float* We  = (const float*)d_in[2];
  const float* Wd  = (const float*)d_in[3];
  const float* v   = (const float*)d_in[4];

  float* out_ctx  = (float*)d_out;
  float* out_attn = out_ctx + B_N * E_N;

  float* sp   = (float*)d_ws;                         // 4 x 131072 f32 partials
  float* decp = sp + 4 * (size_t)SPN;                 // 32768 f32
  unsigned short* Wp = (unsigned short*)(decp + B_N * A_N);  // 262144 bf16 packed

  k_pack   <<<128, 256, 0, stream>>>(We, Wp);
  k_decproj<<<B_N, 256, 0, stream>>>(dh, Wd, decp);
  k_scores <<<4096, 256, 0, stream>>>(enc, Wp, decp, v, sp);
  k_softmax<<<B_N, 256, 0, stream>>>(sp, out_attn);
  k_context<<<B_N * 4, 512, 0, stream>>>(enc, out_attn, out_ctx);
}